// Round 6
// baseline (531.859 us; speedup 1.0000x reference)
//
#include <hip/hip_runtime.h>
#include <hip/hip_cooperative_groups.h>

namespace cg = cooperative_groups;
typedef float f32x4 __attribute__((ext_vector_type(4)));

#define NB 512   // partial-max blocks per table (fallback path)

// ============================================================================
// Cooperative fused kernel: max -> build -> gather with grid.sync() between.
// ws layout: px[1024] | py[1024] | cx[rows*64] | cy[rows*64]
// ============================================================================
__global__ __launch_bounds__(256, 8) void fused_all(
    const int* __restrict__ pos,
    const float* __restrict__ fixedt,
    const float* __restrict__ tx,
    const float* __restrict__ ty,
    float* __restrict__ ws,
    f32x4* __restrict__ out,
    int n_table, int rows, int total4)
{
    cg::grid_group grid = cg::this_grid();
    float* px = ws;
    float* py = ws + 1024;
    float* cx = ws + 2048;
    float* cy = cx + rows * 64;
    const int nb  = gridDim.x;
    const int nbx = nb >> 1;

    // ---- phase 1: per-block partial maxes ----
    {
        const bool isx = (int)blockIdx.x < nbx;
        const float* t = isx ? tx : ty;
        float* dst = isx ? px : py;
        const int b = isx ? blockIdx.x : blockIdx.x - nbx;
        const int stride = nbx * 256;
        float m = -INFINITY;
        for (int i = b * 256 + threadIdx.x; i < n_table; i += stride)
            m = fmaxf(m, t[i]);
        #pragma unroll
        for (int off = 32; off > 0; off >>= 1)
            m = fmaxf(m, __shfl_down(m, off, 64));
        __shared__ float sm[4];
        const int lane = threadIdx.x & 63, wid = threadIdx.x >> 6;
        if (lane == 0) sm[wid] = m;
        __syncthreads();
        if (threadIdx.x == 0)
            dst[b] = fmaxf(fmaxf(sm[0], sm[1]), fmaxf(sm[2], sm[3]));
    }
    __threadfence();
    grid.sync();

    // ---- phase 2: every block reduces partials -> scales; build tables ----
    float sx, sy;
    {
        float mx = -INFINITY, my = -INFINITY;
        for (int k = threadIdx.x; k < nbx; k += 256) {
            mx = fmaxf(mx, px[k]);
            my = fmaxf(my, py[k]);
        }
        #pragma unroll
        for (int off = 32; off > 0; off >>= 1) {
            mx = fmaxf(mx, __shfl_down(mx, off, 64));
            my = fmaxf(my, __shfl_down(my, off, 64));
        }
        __shared__ float smx[4], smy[4];
        const int lane = threadIdx.x & 63, wid = threadIdx.x >> 6;
        if (lane == 0) { smx[wid] = mx; smy[wid] = my; }
        __syncthreads();
        sx = 0.1f / fmaxf(fmaxf(smx[0], smx[1]), fmaxf(smx[2], smx[3]));
        sy = 0.1f / fmaxf(fmaxf(smy[0], smy[1]), fmaxf(smy[2], smy[3]));
    }
    {
        const int btot = rows * 64;
        const int stride = nb * 256;
        for (int i = blockIdx.x * 256 + threadIdx.x; i < btot; i += stride) {
            const int p = i >> 6, j = i & 63;
            const float2 fv = *reinterpret_cast<const float2*>(fixedt + p * 128 + 2 * j);
            const float2 xv = *reinterpret_cast<const float2*>(tx     + p * 128 + 2 * j);
            const float2 yv = *reinterpret_cast<const float2*>(ty     + p * 128 + 2 * j);
            const float f = fv.x + fv.y;
            cx[i] = sx * (xv.x + xv.y) + f;
            cy[i] = sy * (yv.x + yv.y) + f;
        }
    }
    __threadfence();
    grid.sync();

    // ---- phase 3: float4 gather ----
    {
        const f32x4* __restrict__ cx4 = (const f32x4*)cx;
        const f32x4* __restrict__ cy4 = (const f32x4*)cy;
        const int stride = nb * 256;                 // multiple of 32
        const int i0 = blockIdx.x * 256 + threadIdx.x;
        const int  q    = i0 & 31;
        const bool isx  = (q < 16);
        const f32x4* __restrict__ tab = isx ? cx4 : cy4;
        const int  j    = isx ? q : q - 16;
        const int  poff = isx ? 0 : 1;
        const int  rowstep = stride >> 5;
        int row = i0 >> 5;
        for (int i = i0; i < total4; i += stride, row += rowstep) {
            int p = pos[2 * row + poff];             // 16-lane-uniform broadcast
            if (p < 0) p = 1;
            out[i] = tab[p * 16 + j];
        }
    }
}

// ============================================================================
// Fallback path (no cooperative launch): 3 dispatches, as in R5.
// ============================================================================
__global__ void table_max_partial(const float* __restrict__ tx,
                                  const float* __restrict__ ty,
                                  int n, float* __restrict__ px,
                                  float* __restrict__ py) {
    const bool isx = (int)blockIdx.x < NB;
    const float* t = isx ? tx : ty;
    float* dst = isx ? px : py;
    const int b = isx ? blockIdx.x : blockIdx.x - NB;
    const int stride = NB * blockDim.x;
    float m = -INFINITY;
    for (int i = b * blockDim.x + threadIdx.x; i < n; i += stride)
        m = fmaxf(m, t[i]);
    #pragma unroll
    for (int off = 32; off > 0; off >>= 1)
        m = fmaxf(m, __shfl_down(m, off, 64));
    __shared__ float sm[4];
    int lane = threadIdx.x & 63, wid = threadIdx.x >> 6;
    if (lane == 0) sm[wid] = m;
    __syncthreads();
    if (threadIdx.x == 0)
        dst[b] = fmaxf(fmaxf(sm[0], sm[1]), fmaxf(sm[2], sm[3]));
}

__device__ void reduce_scales(const float* __restrict__ px,
                              const float* __restrict__ py,
                              float& sx, float& sy) {
    float mx = fmaxf(px[threadIdx.x], px[threadIdx.x + 256]);
    float my = fmaxf(py[threadIdx.x], py[threadIdx.x + 256]);
    #pragma unroll
    for (int off = 32; off > 0; off >>= 1) {
        mx = fmaxf(mx, __shfl_down(mx, off, 64));
        my = fmaxf(my, __shfl_down(my, off, 64));
    }
    __shared__ float smx[4], smy[4];
    int lane = threadIdx.x & 63, wid = threadIdx.x >> 6;
    if (lane == 0) { smx[wid] = mx; smy[wid] = my; }
    __syncthreads();
    const float fmx = fmaxf(fmaxf(smx[0], smx[1]), fmaxf(smx[2], smx[3]));
    const float fmy = fmaxf(fmaxf(smy[0], smy[1]), fmaxf(smy[2], smy[3]));
    sx = 0.1f / fmx;
    sy = 0.1f / fmy;
}

__global__ void build_kernel(const float* __restrict__ fixedt,
                             const float* __restrict__ tx,
                             const float* __restrict__ ty,
                             const float* __restrict__ px,
                             const float* __restrict__ py,
                             float* __restrict__ cx, float* __restrict__ cy,
                             int total) {
    float sx, sy;
    reduce_scales(px, py, sx, sy);
    const int stride = gridDim.x * blockDim.x;
    for (int i = blockIdx.x * blockDim.x + threadIdx.x; i < total; i += stride) {
        const int p = i >> 6, j = i & 63;
        const float2 fv = *reinterpret_cast<const float2*>(fixedt + p * 128 + 2 * j);
        const float2 xv = *reinterpret_cast<const float2*>(tx     + p * 128 + 2 * j);
        const float2 yv = *reinterpret_cast<const float2*>(ty     + p * 128 + 2 * j);
        const float f = fv.x + fv.y;
        cx[i] = sx * (xv.x + xv.y) + f;
        cy[i] = sy * (yv.x + yv.y) + f;
    }
}

__global__ void gather_kernel(const int* __restrict__ pos,
                              const f32x4* __restrict__ cx,
                              const f32x4* __restrict__ cy,
                              f32x4* __restrict__ out, int total4) {
    const int stride = gridDim.x * blockDim.x;
    const int i0 = blockIdx.x * blockDim.x + threadIdx.x;
    const int  q    = i0 & 31;
    const bool isx  = (q < 16);
    const f32x4* __restrict__ tab = isx ? cx : cy;
    const int  j    = isx ? q : q - 16;
    const int  poff = isx ? 0 : 1;
    const int  rowstep = stride >> 5;
    int row = i0 >> 5;
    for (int i = i0; i < total4; i += stride, row += rowstep) {
        int p = pos[2 * row + poff];
        if (p < 0) p = 1;
        out[i] = tab[p * 16 + j];
    }
}

extern "C" void kernel_launch(void* const* d_in, const int* in_sizes, int n_in,
                              void* d_out, int out_size, void* d_ws, size_t ws_size,
                              hipStream_t stream) {
    const int*   pos    = (const int*)  d_in[0];   // [16,512,32,2]
    const float* fixedt = (const float*)d_in[1];   // [table_len,128]
    const float* tx     = (const float*)d_in[2];
    const float* ty     = (const float*)d_in[3];
    f32x4* out = (f32x4*)d_out;
    float* ws  = (float*)d_ws;

    int n_table = in_sizes[2];                     // table_len * 128
    int rows    = n_table >> 7;                    // table_len
    int total4  = out_size >> 2;

    const size_t need = (2048 + (size_t)rows * 128) * 4;

    // decide path from attributes only (no reliance on launch failure)
    int dev = 0;
    (void)hipGetDevice(&dev);
    int coop = 0, ncu = 0;
    (void)hipDeviceGetAttribute(&coop, hipDeviceAttributeCooperativeLaunch, dev);
    (void)hipDeviceGetAttribute(&ncu, hipDeviceAttributeMultiprocessorCount, dev);
    int maxB = 0;
    (void)hipOccupancyMaxActiveBlocksPerMultiprocessor(&maxB, fused_all, 256, 0);

    if (coop && maxB >= 1 && ncu >= 1 && ws_size >= need) {
        int nb = maxB * ncu;
        if (nb > 2048) nb = 2048;
        nb &= ~1;                                  // even, for the x/y split
        if (nb < 2) nb = 2;
        void* args[] = {(void*)&pos, (void*)&fixedt, (void*)&tx, (void*)&ty,
                        (void*)&ws, (void*)&out, (void*)&n_table, (void*)&rows,
                        (void*)&total4};
        (void)hipLaunchCooperativeKernel((const void*)fused_all, dim3(nb), dim3(256),
                                         args, 0, stream);
    } else {
        // fallback: 3 dispatches
        float* px = ws;
        float* py = px + NB;
        float* cx = py + NB;
        float* cy = cx + (size_t)rows * 64;
        table_max_partial<<<2 * NB, 256, 0, stream>>>(tx, ty, n_table, px, py);
        int btot = rows * 64;
        build_kernel<<<(btot + 255) / 256, 256, 0, stream>>>(fixedt, tx, ty, px, py,
                                                             cx, cy, btot);
        gather_kernel<<<2048, 256, 0, stream>>>(pos, (const f32x4*)cx, (const f32x4*)cy,
                                                out, total4);
    }
}

// Round 7
// 43.083 us; speedup vs baseline: 12.3449x; 12.3449x over previous
//
#include <hip/hip_runtime.h>

typedef float f32x4 __attribute__((ext_vector_type(4)));

#define NBP 256   // partial-max blocks per table

// ---- pass 1: per-block partial maxes, f32x4 loads ----
// grid = 2*NBP blocks: first NBP -> tx partials, next NBP -> ty partials.
__global__ void table_max_partial(const float* __restrict__ tx,
                                  const float* __restrict__ ty,
                                  int n4 /* n_table/4 */,
                                  float* __restrict__ px,
                                  float* __restrict__ py) {
    const bool isx = (int)blockIdx.x < NBP;
    const f32x4* t = (const f32x4*)(isx ? tx : ty);
    float* dst = isx ? px : py;
    const int b = isx ? blockIdx.x : blockIdx.x - NBP;
    const int stride = NBP * blockDim.x;
    float m = -INFINITY;
    for (int i = b * blockDim.x + threadIdx.x; i < n4; i += stride) {
        const f32x4 v = t[i];
        m = fmaxf(m, fmaxf(fmaxf(v.x, v.y), fmaxf(v.z, v.w)));
    }
    #pragma unroll
    for (int off = 32; off > 0; off >>= 1)
        m = fmaxf(m, __shfl_down(m, off, 64));
    __shared__ float sm[4];
    const int lane = threadIdx.x & 63, wid = threadIdx.x >> 6;
    if (lane == 0) sm[wid] = m;
    __syncthreads();
    if (threadIdx.x == 0)
        dst[b] = fmaxf(fmaxf(sm[0], sm[1]), fmaxf(sm[2], sm[3]));
}

// ---- block-wide reduce of partials -> (sx, sy); blockDim == 256 == NBP ----
__device__ void reduce_scales(const float* __restrict__ px,
                              const float* __restrict__ py,
                              float& sx, float& sy) {
    float mx = px[threadIdx.x];
    float my = py[threadIdx.x];
    #pragma unroll
    for (int off = 32; off > 0; off >>= 1) {
        mx = fmaxf(mx, __shfl_down(mx, off, 64));
        my = fmaxf(my, __shfl_down(my, off, 64));
    }
    __shared__ float smx[4], smy[4];
    const int lane = threadIdx.x & 63, wid = threadIdx.x >> 6;
    if (lane == 0) { smx[wid] = mx; smy[wid] = my; }
    __syncthreads();
    sx = 0.1f / fmaxf(fmaxf(smx[0], smx[1]), fmaxf(smx[2], smx[3]));
    sy = 0.1f / fmaxf(fmaxf(smy[0], smy[1]), fmaxf(smy[2], smy[3]));
}

// ---- pass 2: build pair-summed combined tables (each [rows][64] f32) ----
__global__ void build_kernel(const float* __restrict__ fixedt,
                             const float* __restrict__ tx,
                             const float* __restrict__ ty,
                             const float* __restrict__ px,
                             const float* __restrict__ py,
                             float* __restrict__ cx, float* __restrict__ cy,
                             int total /* rows*64 */) {
    float sx, sy;
    reduce_scales(px, py, sx, sy);
    const int stride = gridDim.x * blockDim.x;
    for (int i = blockIdx.x * blockDim.x + threadIdx.x; i < total; i += stride) {
        const int p = i >> 6, j = i & 63;
        const float2 fv = *reinterpret_cast<const float2*>(fixedt + p * 128 + 2 * j);
        const float2 xv = *reinterpret_cast<const float2*>(tx     + p * 128 + 2 * j);
        const float2 yv = *reinterpret_cast<const float2*>(ty     + p * 128 + 2 * j);
        const float f = fv.x + fv.y;
        cx[i] = sx * (xv.x + xv.y) + f;
        cy[i] = sy * (yv.x + yv.y) + f;
    }
}

// ---- pass 3: gather, 32 B per thread (two f32x4 loads + two stores) ----
// float8 index i: row = i>>4, q = i&15. q<8 -> cx, else cy. j = float8 slot in half-row.
__global__ void gather_kernel(const int* __restrict__ pos,
                              const f32x4* __restrict__ cx,
                              const f32x4* __restrict__ cy,
                              f32x4* __restrict__ out, int total8) {
    const int stride = gridDim.x * blockDim.x;      // multiple of 16
    const int i0 = blockIdx.x * blockDim.x + threadIdx.x;
    const int  q    = i0 & 15;
    const bool isx  = (q < 8);
    const f32x4* __restrict__ tab = isx ? cx : cy;
    const int  j2   = (isx ? q : q - 8) * 2;        // f32x4 slot within row (0..15)
    const int  poff = isx ? 0 : 1;
    const int  rowstep = stride >> 4;

    int row = i0 >> 4;
    for (int i = i0; i < total8; i += stride, row += rowstep) {
        int p = pos[2 * row + poff];                // 8-lane-uniform broadcast
        if (p < 0) p = 1;
        const f32x4* src = tab + p * 16 + j2;
        const f32x4 v0 = src[0];
        const f32x4 v1 = src[1];
        out[2 * i + 0] = v0;
        out[2 * i + 1] = v1;
    }
}

extern "C" void kernel_launch(void* const* d_in, const int* in_sizes, int n_in,
                              void* d_out, int out_size, void* d_ws, size_t ws_size,
                              hipStream_t stream) {
    const int*   pos    = (const int*)  d_in[0];   // [16,512,32,2]
    const float* fixedt = (const float*)d_in[1];   // [table_len,128]
    const float* tx     = (const float*)d_in[2];
    const float* ty     = (const float*)d_in[3];
    f32x4* out = (f32x4*)d_out;

    const int n_table  = in_sizes[2];              // table_len * 128
    const int rows     = n_table >> 7;             // table_len
    const int total8   = out_size >> 3;            // 32B units

    // ws layout: px[NBP], py[NBP], then cx[rows*64], cy[rows*64]
    float* px = (float*)d_ws;
    float* py = px + NBP;
    float* cx = py + NBP;
    float* cy = cx + (size_t)rows * 64;

    table_max_partial<<<2 * NBP, 256, 0, stream>>>(tx, ty, n_table >> 2, px, py);

    const int btot = rows * 64;
    build_kernel<<<(btot + 255) / 256, 256, 0, stream>>>(fixedt, tx, ty, px, py,
                                                         cx, cy, btot);
    gather_kernel<<<2048, 256, 0, stream>>>(pos, (const f32x4*)cx, (const f32x4*)cy,
                                            out, total8);
}

// Round 8
// 41.716 us; speedup vs baseline: 12.7495x; 1.0328x over previous
//
#include <hip/hip_runtime.h>

typedef float f32x4 __attribute__((ext_vector_type(4)));

#define NBP 128   // partial-max blocks per table

// ---- pass 1: per-block partial maxes, f32x4 loads ----
// grid = 2*NBP blocks: first NBP -> tx partials, next NBP -> ty partials.
__global__ __launch_bounds__(256) void table_max_partial(
        const float* __restrict__ tx,
        const float* __restrict__ ty,
        int n4 /* n_table/4 */,
        float* __restrict__ px,
        float* __restrict__ py) {
    const bool isx = (int)blockIdx.x < NBP;
    const f32x4* t = (const f32x4*)(isx ? tx : ty);
    float* dst = isx ? px : py;
    const int b = isx ? blockIdx.x : blockIdx.x - NBP;
    const int stride = NBP * 256;
    float m = -INFINITY;
    for (int i = b * 256 + threadIdx.x; i < n4; i += stride) {
        const f32x4 v = t[i];
        m = fmaxf(m, fmaxf(fmaxf(v.x, v.y), fmaxf(v.z, v.w)));
    }
    #pragma unroll
    for (int off = 32; off > 0; off >>= 1)
        m = fmaxf(m, __shfl_down(m, off, 64));
    __shared__ float sm[4];
    const int lane = threadIdx.x & 63, wid = threadIdx.x >> 6;
    if (lane == 0) sm[wid] = m;
    __syncthreads();
    if (threadIdx.x == 0)
        dst[b] = fmaxf(fmaxf(sm[0], sm[1]), fmaxf(sm[2], sm[3]));
}

// ---- block-wide reduce of partials -> (sx, sy); NBP=128 <= blockDim ----
__device__ void reduce_scales(const float* __restrict__ px,
                              const float* __restrict__ py,
                              float& sx, float& sy) {
    float mx = (threadIdx.x < NBP) ? px[threadIdx.x] : -INFINITY;
    float my = (threadIdx.x < NBP) ? py[threadIdx.x] : -INFINITY;
    #pragma unroll
    for (int off = 32; off > 0; off >>= 1) {
        mx = fmaxf(mx, __shfl_down(mx, off, 64));
        my = fmaxf(my, __shfl_down(my, off, 64));
    }
    __shared__ float smx[4], smy[4];
    const int lane = threadIdx.x & 63, wid = threadIdx.x >> 6;
    if (lane == 0) { smx[wid] = mx; smy[wid] = my; }
    __syncthreads();
    sx = 0.1f / fmaxf(fmaxf(smx[0], smx[1]), fmaxf(smx[2], smx[3]));
    sy = 0.1f / fmaxf(fmaxf(smy[0], smy[1]), fmaxf(smy[2], smy[3]));
}

// ---- pass 2: build combined tables, f32x4 per thread ----
// c-element f32x4 index i: p = i>>4, j4 = i&15. Reads 8 floats from each src.
__global__ __launch_bounds__(256) void build_kernel(
        const float* __restrict__ fixedt,
        const float* __restrict__ tx,
        const float* __restrict__ ty,
        const float* __restrict__ px,
        const float* __restrict__ py,
        f32x4* __restrict__ cx, f32x4* __restrict__ cy,
        int total16 /* rows*16 */) {
    float sx, sy;
    reduce_scales(px, py, sx, sy);
    const f32x4* fx4 = (const f32x4*)fixedt;
    const f32x4* tx4 = (const f32x4*)tx;
    const f32x4* ty4 = (const f32x4*)ty;
    const int stride = gridDim.x * blockDim.x;
    for (int i = blockIdx.x * blockDim.x + threadIdx.x; i < total16; i += stride) {
        // source f32x4 pair indices: 2i, 2i+1  (8 consecutive floats)
        const f32x4 f0 = fx4[2 * i], f1 = fx4[2 * i + 1];
        const f32x4 x0 = tx4[2 * i], x1 = tx4[2 * i + 1];
        const f32x4 y0 = ty4[2 * i], y1 = ty4[2 * i + 1];
        f32x4 cxv, cyv;
        cxv.x = sx * (x0.x + x0.y) + (f0.x + f0.y);
        cxv.y = sx * (x0.z + x0.w) + (f0.z + f0.w);
        cxv.z = sx * (x1.x + x1.y) + (f1.x + f1.y);
        cxv.w = sx * (x1.z + x1.w) + (f1.z + f1.w);
        cyv.x = sy * (y0.x + y0.y) + (f0.x + f0.y);
        cyv.y = sy * (y0.z + y0.w) + (f0.z + f0.w);
        cyv.z = sy * (y1.x + y1.y) + (f1.x + f1.y);
        cyv.w = sy * (y1.z + y1.w) + (f1.z + f1.w);
        cx[i] = cxv;
        cy[i] = cyv;
    }
}

// ---- pass 3: pure float4 gather (R5-proven form, untouched) ----
__global__ __launch_bounds__(256) void gather_kernel(
        const int* __restrict__ pos,
        const f32x4* __restrict__ cx,
        const f32x4* __restrict__ cy,
        f32x4* __restrict__ out, int total4) {
    const int stride = gridDim.x * blockDim.x;      // multiple of 32
    const int i0 = blockIdx.x * blockDim.x + threadIdx.x;
    const int  q    = i0 & 31;
    const bool isx  = (q < 16);
    const f32x4* __restrict__ tab = isx ? cx : cy;
    const int  j    = isx ? q : q - 16;
    const int  poff = isx ? 0 : 1;
    const int  rowstep = stride >> 5;
    int row = i0 >> 5;
    for (int i = i0; i < total4; i += stride, row += rowstep) {
        int p = pos[2 * row + poff];                // 16-lane-uniform broadcast
        if (p < 0) p = 1;
        out[i] = tab[p * 16 + j];
    }
}

extern "C" void kernel_launch(void* const* d_in, const int* in_sizes, int n_in,
                              void* d_out, int out_size, void* d_ws, size_t ws_size,
                              hipStream_t stream) {
    const int*   pos    = (const int*)  d_in[0];   // [16,512,32,2]
    const float* fixedt = (const float*)d_in[1];   // [table_len,128]
    const float* tx     = (const float*)d_in[2];
    const float* ty     = (const float*)d_in[3];
    f32x4* out = (f32x4*)d_out;

    const int n_table  = in_sizes[2];              // table_len * 128
    const int rows     = n_table >> 7;             // table_len
    const int total4   = out_size >> 2;

    // ws layout: px[NBP], py[NBP], then cx[rows*64], cy[rows*64] (16B aligned)
    float* px = (float*)d_ws;
    float* py = px + NBP;
    f32x4* cx = (f32x4*)(py + NBP);
    f32x4* cy = cx + (size_t)rows * 16;

    table_max_partial<<<2 * NBP, 256, 0, stream>>>(tx, ty, n_table >> 2, px, py);

    const int btot16 = rows * 16;                  // f32x4 count per combined table
    build_kernel<<<(btot16 + 255) / 256, 256, 0, stream>>>(fixedt, tx, ty, px, py,
                                                           cx, cy, btot16);
    gather_kernel<<<2048, 256, 0, stream>>>(pos, (const f32x4*)cx, (const f32x4*)cy,
                                            out, total4);
}